// Round 1
// 537.537 us; speedup vs baseline: 1.3411x; 1.3411x over previous
//
#include <hip/hip_runtime.h>
#include <hip/hip_bf16.h>
#include <cstddef>

// Problem constants (LiteFlowNetCorr): B=8, C=128, H=128, W=224, R=4
#define BN 8
#define CCH 128
#define HH 128
#define WW 224
#define ND 81            // (2R+1)^2 displacements
#define CINP1 224        // conv1 K padded: 128 (x1) + 81 (corr) + 15 zeros

typedef __attribute__((ext_vector_type(8))) short short8_t;   // 8 bf16
typedef __attribute__((ext_vector_type(4))) float float4_t;   // MFMA acc

static __device__ __forceinline__ unsigned short f2bf(float f) {
  __hip_bfloat16 h = __float2bfloat16(f);
  return *(unsigned short*)&h;
}
static __device__ __forceinline__ float bf2f(short s) {
  unsigned u = ((unsigned)(unsigned short)s) << 16;
  return __uint_as_float(u);
}

// ---------------------------------------------------------------------------
// convert_x1: x1 fp32 NCHW -> A0 bf16 NHWC (channels 0..127), zero-fill the
// pad chunks so channels 209..223 are 0 (corr later fills 128..208).
// A0 record = 224 ch * 2B = 448 B = 28 uint4 chunks per pixel.
// ---------------------------------------------------------------------------
__global__ __launch_bounds__(256) void convert_x1(
    const float* __restrict__ x1, uint4* __restrict__ a0q) {
  const int g = blockIdx.x * 256 + threadIdx.x;  // pixel id 0..229375
  const int hw = HH * WW;
  const int b = g / hw, px = g - b * hw;
  const float* src = x1 + (size_t)b * CCH * hw + px;

  uint4 zero; zero.x = zero.y = zero.z = zero.w = 0u;
#pragma unroll
  for (int cq = 0; cq < 16; ++cq) {  // 16 chunks = 128 channels
    unsigned r[4];
#pragma unroll
    for (int j = 0; j < 4; ++j) {
      const int c = cq * 8 + j * 2;
      const float f0 = src[(size_t)(c + 0) * hw];
      const float f1 = src[(size_t)(c + 1) * hw];
      r[j] = (unsigned)f2bf(f0) | ((unsigned)f2bf(f1) << 16);
    }
    uint4 u; u.x = r[0]; u.y = r[1]; u.z = r[2]; u.w = r[3];
    a0q[(size_t)g * 28 + cq] = u;
  }
  a0q[(size_t)g * 28 + 26] = zero;  // ch 208..215 (corr overwrites ch208)
  a0q[(size_t)g * 28 + 27] = zero;  // ch 216..223
}

// ---------------------------------------------------------------------------
// corr_mfma: correlation as banded implicit GEMM on the matrix pipe.
//
// For output row y and displacement row dy, corr over x/dx is a band of the
// GEMM  O[m][n] = sum_c x1[c, y, x0+m] * x2[c, y+dy-4, x0-4+n],  n in [0,24).
// Valid outputs: dx = n - m in [0,8]. Computed as two 16x16x32 bf16 MFMA
// N-tiles (n in [0,16) and [8,24)) per 32-channel block; 28% of MFMA slots
// are useful, but MFMA runs ~15x the fp32 VALU rate -> compute is free.
//
// Block: 512 thr = 8 waves, 16x16 px tile; wave w owns y rows 2w, 2w+1.
// Per 32-ch block: stage x2 halo 24x24 px as bf16 SoA chunks sB[q][r][c]
// (uint4 = 8ch), 36.9 KB LDS. B-frag read = 1 ds_read_b128, all offsets are
// immediates off one per-lane base. A-frags read from A0's x1 channels
// (bf16 NHWC, written by convert_x1). acc[2][9][2] float4 = 144 VGPR.
// Epilogue: extract the 9 diagonals, bf16 scatter into A0 ch 128..208.
// ---------------------------------------------------------------------------
__global__ __launch_bounds__(512, 2) void corr_mfma(
    const float* __restrict__ x2,
    const uint4* __restrict__ a0q,          // x1 bf16 NHWC = chunks 0..15
    __hip_bfloat16* __restrict__ a0) {      // corr out: channels 128..208
  __shared__ uint4 sB[4 * 576];  // [q][r*24+c], one 32-ch block at a time
  const int tid = threadIdx.x;
  const int lane = tid & 63, w = tid >> 6;   // 8 waves
  const int m = lane & 15, q = lane >> 4;    // MFMA operand lane split
  const int x0 = blockIdx.x * 16, y0 = blockIdx.y * 16, b = blockIdx.z;
  const int hw = HH * WW;

  float4_t acc[2][9][2];
#pragma unroll
  for (int yy = 0; yy < 2; ++yy)
#pragma unroll
    for (int d = 0; d < 9; ++d)
#pragma unroll
      for (int t = 0; t < 2; ++t) acc[yy][d][t] = (float4_t)0.0f;

  for (int cb = 0; cb < 4; ++cb) {  // 4 blocks of 32 channels
    __syncthreads();
    // --- stage x2 halo: 24x24 px, ch cb*32..cb*32+31, 4 q-planes of uint4 ---
    for (int s = tid; s < 2304; s += 512) {
      const int qs = s / 576, rc = s - qs * 576;
      const int r = rc / 24, c = rc - r * 24;
      const int gy = y0 - 4 + r, gx = x0 - 4 + c;
      uint4 u; u.x = u.y = u.z = u.w = 0u;
      if (gy >= 0 && gy < HH && gx >= 0 && gx < WW) {
        const float* p2 =
            x2 + (size_t)(b * CCH + cb * 32 + qs * 8) * hw + gy * WW + gx;
        unsigned rr[4];
#pragma unroll
        for (int j = 0; j < 4; ++j) {
          const float f0 = p2[(size_t)(2 * j + 0) * hw];
          const float f1 = p2[(size_t)(2 * j + 1) * hw];
          rr[j] = (unsigned)f2bf(f0) | ((unsigned)f2bf(f1) << 16);
        }
        u.x = rr[0]; u.y = rr[1]; u.z = rr[2]; u.w = rr[3];
      }
      sB[s] = u;
    }
    __syncthreads();

    // --- A-fragments: this wave's two x1 rows, from A0 (bf16 NHWC) ---
    uint4 afr[2];
#pragma unroll
    for (int yy = 0; yy < 2; ++yy) {
      const int y = y0 + 2 * w + yy;
      afr[yy] = a0q[((size_t)(b * HH + y) * WW + x0 + m) * 28 + cb * 4 + q];
    }

#pragma unroll
    for (int yy = 0; yy < 2; ++yy) {
      const short8_t af = *(const short8_t*)&afr[yy];
#pragma unroll
      for (int dyi = 0; dyi < 9; ++dyi) {
        const int r = 2 * w + yy + dyi;  // LDS halo row (y - y0) + dyi
#pragma unroll
        for (int t = 0; t < 2; ++t) {
          const short8_t bf =
              *(const short8_t*)&sB[q * 576 + r * 24 + 8 * t + m];
          acc[yy][dyi][t] = __builtin_amdgcn_mfma_f32_16x16x32_bf16(
              af, bf, acc[yy][dyi][t], 0, 0, 0);
        }
      }
    }
  }

  // --- epilogue: extract diagonals dx = n - m in [0,8], scatter bf16 ---
  // C/D layout: col(n) = lane&15 (=m var), row(mm) = (lane>>4)*4 + reg.
  const float sc = 1.0f / 128.0f;
#pragma unroll
  for (int yy = 0; yy < 2; ++yy) {
    const int y = y0 + 2 * w + yy;
    __hip_bfloat16* dst = a0 + ((size_t)(b * HH + y) * WW + x0) * CINP1;
#pragma unroll
    for (int dyi = 0; dyi < 9; ++dyi) {
#pragma unroll
      for (int t = 0; t < 2; ++t) {
#pragma unroll
        for (int r = 0; r < 4; ++r) {
          const int mm = 4 * q + r;           // output pixel offset
          const int nabs = 8 * t + m;         // absolute x2 column offset
          const int dxi = nabs - mm;
          // t0 covers nabs<16; t1 covers nabs>=16 (dedupe overlap at m<8)
          if (dxi >= 0 && dxi <= 8 && (t == 0 || m >= 8)) {
            dst[(size_t)mm * CINP1 + 128 + dyi * 9 + dxi] =
                __float2bfloat16(acc[yy][dyi][t][r] * sc);
          }
        }
      }
    }
  }
}

// ---------------------------------------------------------------------------
// Weight repack: OIHW fp32 -> bf16 [tap][cout][cin_pad] (zero-pad cin tail).
// ---------------------------------------------------------------------------
__global__ void repack_w_bf16(const float* __restrict__ w,
                              __hip_bfloat16* __restrict__ wt,
                              int COUT, int CIN, int CINPAD) {
  const int idx = blockIdx.x * 256 + threadIdx.x;
  const int n = 9 * COUT * CINPAD;
  if (idx >= n) return;
  const int t = idx / (COUT * CINPAD);
  const int rem = idx - t * (COUT * CINPAD);
  const int co = rem / CINPAD;
  const int ci = rem - co * CINPAD;
  const float v = (ci < CIN) ? w[(size_t)(co * CIN + ci) * 9 + t] : 0.0f;
  wt[idx] = __float2bfloat16(v);
}

// ---------------------------------------------------------------------------
// conv_mfma: implicit-GEMM 3x3 SAME conv, bf16 NHWC in -> bf16 NHWC out.
// Block: 256 thr = 4 waves; out tile 16x16 px; wave w owns y-rows 4w..4w+3.
// K loop: cin blocks of 32; per cb stage A halo (18x18 px, 32ch) and W chunk
// ([9][COUT][32]) in LDS as SoA 16B chunks (2-way max bank aliasing).
// MFMA 16x16x32 bf16: A[m=px_x][k=cin], B[k][n=cout].
// ---------------------------------------------------------------------------
template <int CINPAD, int COUT, bool LEAKY>
__global__ __launch_bounds__(256, 2) void conv_mfma(
    const uint4* __restrict__ inq,          // bf16 NHWC, CINPAD ch/px
    const __hip_bfloat16* __restrict__ wt,  // [9][COUT][CINPAD]
    const float* __restrict__ bias,
    __hip_bfloat16* __restrict__ out) {     // bf16 NHWC, COUT ch/px
  constexpr int NT = COUT / 16;
  constexpr int NCB = CINPAD / 32;
  constexpr int QSTRIDE_A = 324;          // 18*18 px slots per q-plane
  __shared__ uint4 sA[4 * QSTRIDE_A];     // [q][p]
  __shared__ uint4 sW[4 * 9 * COUT];      // [q][t][co]

  const int tid = threadIdx.x;
  const int lane = tid & 63, w = tid >> 6;
  const int m = lane & 15, q = lane >> 4;
  const int x0 = blockIdx.x * 16, y0 = blockIdx.y * 16, b = blockIdx.z;
  const uint4* wq = (const uint4*)wt;

  float4_t acc[4][NT];
#pragma unroll
  for (int my = 0; my < 4; ++my)
#pragma unroll
    for (int nt = 0; nt < NT; ++nt) acc[my][nt] = (float4_t)0.0f;

  for (int cb = 0; cb < NCB; ++cb) {
    __syncthreads();
    // --- stage A halo tile: 18x18 px, chunks cb*4 .. cb*4+3 ---
    for (int s = tid; s < 324; s += 256) {
      const int pr = s / 18, pc = s - pr * 18;
      const int gy = y0 - 1 + pr, gx = x0 - 1 + pc;
      uint4 c0, c1, c2, c3;
      if (gy >= 0 && gy < HH && gx >= 0 && gx < WW) {
        const size_t base =
            ((size_t)(b * HH + gy) * WW + gx) * (CINPAD / 8) + cb * 4;
        c0 = inq[base + 0]; c1 = inq[base + 1];
        c2 = inq[base + 2]; c3 = inq[base + 3];
      } else {
        c0.x=c0.y=c0.z=c0.w=0u; c1=c0; c2=c0; c3=c0;
      }
      sA[0 * QSTRIDE_A + s] = c0;
      sA[1 * QSTRIDE_A + s] = c1;
      sA[2 * QSTRIDE_A + s] = c2;
      sA[3 * QSTRIDE_A + s] = c3;
    }
    // --- stage W chunk: [9][COUT][32ch] ---
    for (int s = tid; s < 9 * COUT; s += 256) {
      const int t = s / COUT, co = s - t * COUT;
      const size_t base = ((size_t)(t * COUT + co) * CINPAD + cb * 32) / 8;
      const uint4 c0 = wq[base + 0], c1 = wq[base + 1];
      const uint4 c2 = wq[base + 2], c3 = wq[base + 3];
      sW[(0 * 9 + t) * COUT + co] = c0;
      sW[(1 * 9 + t) * COUT + co] = c1;
      sW[(2 * 9 + t) * COUT + co] = c2;
      sW[(3 * 9 + t) * COUT + co] = c3;
    }
    __syncthreads();

#pragma unroll
    for (int t = 0; t < 9; ++t) {
      const int dy = t / 3 - 1, dx = t % 3 - 1;
      short8_t bf[NT];
#pragma unroll
      for (int nt = 0; nt < NT; ++nt) {
        bf[nt] = *(const short8_t*)&sW[(q * 9 + t) * COUT + nt * 16 + m];
      }
#pragma unroll
      for (int my = 0; my < 4; ++my) {
        const int row = 4 * w + my + dy + 1;
        const int col = m + dx + 1;
        const short8_t af =
            *(const short8_t*)&sA[q * QSTRIDE_A + row * 18 + col];
#pragma unroll
        for (int nt = 0; nt < NT; ++nt) {
          acc[my][nt] = __builtin_amdgcn_mfma_f32_16x16x32_bf16(
              af, bf[nt], acc[my][nt], 0, 0, 0);
        }
      }
    }
  }

  // --- epilogue: bias + leaky + bf16 NHWC store ---
  // C/D layout: col(n)=lane&15, row(m)=(lane>>4)*4+r
#pragma unroll
  for (int my = 0; my < 4; ++my) {
    const int y = y0 + 4 * w + my;
#pragma unroll
    for (int nt = 0; nt < NT; ++nt) {
      const int co = nt * 16 + m;
      const float bv = bias[co];
#pragma unroll
      for (int r = 0; r < 4; ++r) {
        const int x = x0 + q * 4 + r;
        float v = acc[my][nt][r] + bv;
        if (LEAKY) v = (v >= 0.0f) ? v : 0.1f * v;
        out[((size_t)(b * HH + y) * WW + x) * COUT + co] = __float2bfloat16(v);
      }
    }
  }
}

// ---------------------------------------------------------------------------
// conv4: 32 -> 2, direct, bf16 NHWC in -> fp32 NCHW out (final flow).
// ---------------------------------------------------------------------------
__global__ __launch_bounds__(256, 2) void conv4_kernel(
    const uint4* __restrict__ inq,          // h3, 32ch/px = 4 uint4
    const __hip_bfloat16* __restrict__ wt,  // [9][2][32]
    const float* __restrict__ bias,
    float* __restrict__ out) {
  __shared__ uint4 sA[4 * 324];
  __shared__ uint4 sW[9 * 2 * 4];  // [t][co][q]
  const int tid = threadIdx.x;
  const int tx = tid & 15, ty = tid >> 4;
  const int x0 = blockIdx.x * 16, y0 = blockIdx.y * 16, b = blockIdx.z;

  for (int s = tid; s < 324; s += 256) {
    const int pr = s / 18, pc = s - pr * 18;
    const int gy = y0 - 1 + pr, gx = x0 - 1 + pc;
    uint4 c0, c1, c2, c3;
    if (gy >= 0 && gy < HH && gx >= 0 && gx < WW) {
      const size_t base = ((size_t)(b * HH + gy) * WW + gx) * 4;
      c0 = inq[base + 0]; c1 = inq[base + 1];
      c2 = inq[base + 2]; c3 = inq[base + 3];
    } else {
      c0.x=c0.y=c0.z=c0.w=0u; c1=c0; c2=c0; c3=c0;
    }
    sA[0 * 324 + s] = c0; sA[1 * 324 + s] = c1;
    sA[2 * 324 + s] = c2; sA[3 * 324 + s] = c3;
  }
  if (tid < 72) sW[tid] = ((const uint4*)wt)[tid];
  __syncthreads();

  float acc0 = bias[0], acc1 = bias[1];
#pragma unroll
  for (int t = 0; t < 9; ++t) {
    const int dy = t / 3 - 1, dx = t % 3 - 1;
    const int row = ty + dy + 1, col = tx + dx + 1;
#pragma unroll
    for (int qi = 0; qi < 4; ++qi) {
      const short8_t a = *(const short8_t*)&sA[qi * 324 + row * 18 + col];
      const short8_t w0 = *(const short8_t*)&sW[(t * 2 + 0) * 4 + qi];
      const short8_t w1 = *(const short8_t*)&sW[(t * 2 + 1) * 4 + qi];
#pragma unroll
      for (int j = 0; j < 8; ++j) {
        const float av = bf2f(a[j]);
        acc0 += av * bf2f(w0[j]);
        acc1 += av * bf2f(w1[j]);
      }
    }
  }
  const int y = y0 + ty, x = x0 + tx;
  out[((size_t)(b * 2 + 0) * HH + y) * WW + x] = acc0;
  out[((size_t)(b * 2 + 1) * HH + y) * WW + x] = acc1;
}

// ---------------------------------------------------------------------------
// Launch
// ---------------------------------------------------------------------------
extern "C" void kernel_launch(void* const* d_in, const int* in_sizes, int n_in,
                              void* d_out, int out_size, void* d_ws,
                              size_t ws_size, hipStream_t stream) {
  const float* x1 = (const float*)d_in[0];
  const float* x2 = (const float*)d_in[1];
  const float* w1 = (const float*)d_in[2];
  const float* b1 = (const float*)d_in[3];
  const float* w2 = (const float*)d_in[4];
  const float* b2 = (const float*)d_in[5];
  const float* w3 = (const float*)d_in[6];
  const float* b3 = (const float*)d_in[7];
  const float* w4 = (const float*)d_in[8];
  const float* b4 = (const float*)d_in[9];
  float* out = (float*)d_out;

  // Workspace (bytes):
  //  A0  [0, 102760448)              bf16 NHWC 224ch concat (x1+corr+pad)
  //  h1  [102760448, 132120576)      bf16 NHWC 64ch
  //  wt1 [132120576, +258048)        bf16 [9][64][224]
  //  wt2 ... [9][64][64], wt3 [9][32][64], wt4 [9][2][32]
  //  h2 reuses A0[0, 29360128)  (A0 dead after conv1)
  //  h3 reuses A0[29360128, 44040192)
  char* ws = (char*)d_ws;
  __hip_bfloat16* A0 = (__hip_bfloat16*)ws;
  const size_t A0_BYTES = (size_t)BN * HH * WW * CINP1 * 2;  // 102,760,448
  __hip_bfloat16* h1 = (__hip_bfloat16*)(ws + A0_BYTES);
  const size_t H1_BYTES = (size_t)BN * HH * WW * 64 * 2;     // 29,360,128
  __hip_bfloat16* wt1 = (__hip_bfloat16*)(ws + A0_BYTES + H1_BYTES);
  __hip_bfloat16* wt2 = wt1 + 9 * 64 * CINP1;
  __hip_bfloat16* wt3 = wt2 + 9 * 64 * 64;
  __hip_bfloat16* wt4 = wt3 + 9 * 32 * 64;
  __hip_bfloat16* h2 = (__hip_bfloat16*)ws;
  __hip_bfloat16* h3 = (__hip_bfloat16*)(ws + H1_BYTES);

  // weight repacks (tiny)
  {
    int n1 = 9 * 64 * CINP1;
    repack_w_bf16<<<(n1 + 255) / 256, 256, 0, stream>>>(w1, wt1, 64, 209, CINP1);
    int n2 = 9 * 64 * 64;
    repack_w_bf16<<<(n2 + 255) / 256, 256, 0, stream>>>(w2, wt2, 64, 64, 64);
    int n3 = 9 * 32 * 64;
    repack_w_bf16<<<(n3 + 255) / 256, 256, 0, stream>>>(w3, wt3, 32, 64, 64);
    int n4 = 9 * 2 * 32;
    repack_w_bf16<<<(n4 + 255) / 256, 256, 0, stream>>>(w4, wt4, 2, 32, 32);
  }

  // x1 -> A0 (bf16 NHWC) + zero pad channels
  convert_x1<<<BN * HH * WW / 256, 256, 0, stream>>>(x1, (uint4*)A0);

  // correlation -> A0 channels 128..208 (banded MFMA GEMM)
  corr_mfma<<<dim3(WW / 16, HH / 16, BN), dim3(512), 0, stream>>>(
      x2, (const uint4*)A0, A0);

  const dim3 grid(WW / 16, HH / 16, BN);  // 14 x 8 x 8 = 896 blocks
  conv_mfma<CINP1, 64, true>
      <<<grid, 256, 0, stream>>>((const uint4*)A0, wt1, b1, h1);
  conv_mfma<64, 64, true>
      <<<grid, 256, 0, stream>>>((const uint4*)h1, wt2, b2, h2);
  conv_mfma<64, 32, true>
      <<<grid, 256, 0, stream>>>((const uint4*)h2, wt3, b3, h3);
  conv4_kernel<<<grid, 256, 0, stream>>>((const uint4*)h3, wt4, b4, out);
}